// Round 3
// baseline (2134.176 us; speedup 1.0000x reference)
//
#include <hip/hip_runtime.h>
#include <math.h>

#define B_ 4
#define N_ 256
#define D_ 128
#define H_ 256
#define K_ 8
#define NJ 128   // j processed per phase (2 phases)

// ---------------------------------------------------------------------------
// Prep kernel: one block per (b,n), 256 threads (thread = h).
//  - Ag[b,n,h]  = s[b,n,:] @ Wg1[0:128,h]   + bg1[h]   (the "i" term, bias folded)
//  - BgT[b,h,n] = s[b,n,:] @ Wg1[128:256,h]            (the "j" term, transposed)
//  - same for the attention net (Aa, BaT)
//  - WgcT[h,d]  = Wg1[256+d,h], WacT[h,d] = Wa1[256+d,h] (wave-uniform weight reads)
// ---------------------------------------------------------------------------
__global__ __launch_bounds__(256) void prep_kernel(
    const float* __restrict__ s,
    const float* __restrict__ Wg1, const float* __restrict__ bg1,
    const float* __restrict__ Wa1, const float* __restrict__ ba1,
    float* __restrict__ Ag, float* __restrict__ BgT,
    float* __restrict__ Aa, float* __restrict__ BaT,
    float* __restrict__ WgcT, float* __restrict__ WacT) {
  const int b = blockIdx.x >> 8;
  const int n = blockIdx.x & 255;
  const int h = threadIdx.x;

  __shared__ float sh[D_];
  if (h < D_) sh[h] = s[(b * N_ + n) * D_ + h];
  __syncthreads();

  float ag = bg1[h], bg = 0.f, aa = ba1[h], ba = 0.f;
#pragma unroll 8
  for (int d = 0; d < D_; d++) {
    const float sd = sh[d];
    ag = fmaf(sd, Wg1[d * H_ + h], ag);              // coalesced over h
    bg = fmaf(sd, Wg1[(D_ + d) * H_ + h], bg);
    aa = fmaf(sd, Wa1[d * H_ + h], aa);
    ba = fmaf(sd, Wa1[(D_ + d) * H_ + h], ba);
  }
  Ag[(b * N_ + n) * H_ + h] = ag;
  BgT[(b * H_ + h) * N_ + n] = bg;
  Aa[(b * N_ + n) * H_ + h] = aa;
  BaT[(b * H_ + h) * N_ + n] = ba;

  if (blockIdx.x < D_) {  // blocks 0..127 also transpose the W1c slabs
    const int d = blockIdx.x;
    WgcT[h * D_ + d] = Wg1[(2 * D_ + d) * H_ + h];
    WacT[h * D_ + d] = Wa1[(2 * D_ + d) * H_ + h];
  }
}

__device__ inline void arg_better(float v2, int i2, float& v, int& idx) {
  if (v2 > v || (v2 == v && i2 < idx)) { v = v2; idx = i2; }
}

// ---------------------------------------------------------------------------
// Main kernel v3: one block per (b,i), 256 threads.
// p lives in LDS (64 KB tile for 128 j), read back via ds_read_b128 at the
// structural floor rate; weights are wave-uniform s_loads. Thread t handles
// j = t&127 and hidden-half (t>>7)*128. Two j-phases cover all 256 j.
// ---------------------------------------------------------------------------
__global__ __launch_bounds__(256, 2) void score_kernel(
    const float* __restrict__ s,
    const float* __restrict__ Ag, const float* __restrict__ BgT,
    const float* __restrict__ Aa, const float* __restrict__ BaT,
    const float* __restrict__ WgcT, const float* __restrict__ WacT,
    const float* __restrict__ Wg2, const float* __restrict__ bg2p,
    const float* __restrict__ Wa2, const float* __restrict__ ba2p,
    float* __restrict__ out) {
  const int b = blockIdx.x >> 8;
  const int i = blockIdx.x & 255;
  const int t = threadIdx.x;
  const int jloc = t & (NJ - 1);
  const int half = t >> 7;            // 0: h in [0,128), 1: h in [128,256)
  const int hbase = half * 128;

  __shared__ float4 p_lds[32 * NJ];   // [c][j], 16 B elems : 64 KB
  __shared__ float si_sh[D_];
  __shared__ float scg_sh[N_];
  __shared__ float attl_sh[N_];
  __shared__ float partg_sh[NJ];
  __shared__ float parta_sh[NJ];
  __shared__ float red_v[4];
  __shared__ int red_i[4];
  __shared__ int sel_list[K_];

  if (t < D_) si_sh[t] = s[(b * N_ + i) * D_ + t];

  const float* __restrict__ Agp = Ag + (b * N_ + i) * H_;
  const float* __restrict__ Aap = Aa + (b * N_ + i) * H_;

#pragma unroll 1
  for (int ph = 0; ph < 2; ph++) {
    const int jglob = ph * NJ + jloc;
    const float4* __restrict__ srow = (const float4*)(s + (b * N_ + jglob) * D_);
    __syncthreads();   // si_sh ready (ph 0) / p_lds readers of prev phase done
    // stage p[j][d] = si[d]*sj[d], each half writes its 16 chunks of 4 floats
#pragma unroll
    for (int c0 = 0; c0 < 16; c0++) {
      const int c = half * 16 + c0;
      const float4 sv = srow[c];
      float4 pv;
      pv.x = si_sh[4 * c + 0] * sv.x;
      pv.y = si_sh[4 * c + 1] * sv.y;
      pv.z = si_sh[4 * c + 2] * sv.z;
      pv.w = si_sh[4 * c + 3] * sv.w;
      p_lds[c * NJ + jloc] = pv;
    }
    __syncthreads();

    float scg = 0.f, sca = 0.f;
#pragma unroll 1
    for (int hh = 0; hh < 128; hh += 8) {       // 16 passes, 8 h per net
      const int h = hbase + hh;
      const float* __restrict__ wg = WgcT + h * D_;   // uniform -> s_load
      const float* __restrict__ wa = WacT + h * D_;
      float hg0 = 0.f, hg1 = 0.f, hg2 = 0.f, hg3 = 0.f;
      float hg4 = 0.f, hg5 = 0.f, hg6 = 0.f, hg7 = 0.f;
      float ha0 = 0.f, ha1 = 0.f, ha2 = 0.f, ha3 = 0.f;
      float ha4 = 0.f, ha5 = 0.f, ha6 = 0.f, ha7 = 0.f;
#pragma unroll
      for (int c = 0; c < 32; c++) {
        const float4 pv = p_lds[c * NJ + jloc];
        const int o = 4 * c;
#define GSTEP(q, acc) \
        acc = fmaf(pv.x, wg[q * D_ + o + 0], acc); \
        acc = fmaf(pv.y, wg[q * D_ + o + 1], acc); \
        acc = fmaf(pv.z, wg[q * D_ + o + 2], acc); \
        acc = fmaf(pv.w, wg[q * D_ + o + 3], acc);
#define ASTEP(q, acc) \
        acc = fmaf(pv.x, wa[q * D_ + o + 0], acc); \
        acc = fmaf(pv.y, wa[q * D_ + o + 1], acc); \
        acc = fmaf(pv.z, wa[q * D_ + o + 2], acc); \
        acc = fmaf(pv.w, wa[q * D_ + o + 3], acc);
        GSTEP(0, hg0) GSTEP(1, hg1) GSTEP(2, hg2) GSTEP(3, hg3)
        GSTEP(4, hg4) GSTEP(5, hg5) GSTEP(6, hg6) GSTEP(7, hg7)
        ASTEP(0, ha0) ASTEP(1, ha1) ASTEP(2, ha2) ASTEP(3, ha3)
        ASTEP(4, ha4) ASTEP(5, ha5) ASTEP(6, ha6) ASTEP(7, ha7)
#undef GSTEP
#undef ASTEP
      }
      const float* __restrict__ BgTp = BgT + (b * H_ + h) * N_ + jglob;
      const float* __restrict__ BaTp = BaT + (b * H_ + h) * N_ + jglob;
#define EPI(q, hgq, haq) \
      { const float hgv = hgq + Agp[h + q] + BgTp[q * N_]; \
        const float hav = haq + Aap[h + q] + BaTp[q * N_]; \
        scg = fmaf(fmaxf(hgv, 0.f), Wg2[h + q], scg); \
        sca = fmaf(fmaxf(hav, 0.f), Wa2[h + q], sca); }
      EPI(0, hg0, ha0) EPI(1, hg1, ha1) EPI(2, hg2, ha2) EPI(3, hg3, ha3)
      EPI(4, hg4, ha4) EPI(5, hg5, ha5) EPI(6, hg6, ha6) EPI(7, hg7, ha7)
#undef EPI
    }

    if (half) { partg_sh[jloc] = scg; parta_sh[jloc] = sca; }
    __syncthreads();
    if (!half) {
      scg_sh[jglob] = scg + partg_sh[jloc] + bg2p[0];
      attl_sh[jglob] = sca + parta_sh[jloc] + ba2p[0];
    }
  }
  __syncthreads();

  // ---- top-8 over j: value desc, index asc (matches jax.lax.top_k set) ----
  for (int k = 0; k < K_; k++) {
    float v = scg_sh[t];
    int idx = t;
#pragma unroll
    for (int off = 32; off > 0; off >>= 1) {
      const float vo = __shfl_down(v, off, 64);
      const int io = __shfl_down(idx, off, 64);
      arg_better(vo, io, v, idx);
    }
    if ((t & 63) == 0) { red_v[t >> 6] = v; red_i[t >> 6] = idx; }
    __syncthreads();
    if (t == 0) {
      float bv = red_v[0];
      int bi = red_i[0];
      for (int w = 1; w < 4; w++) arg_better(red_v[w], red_i[w], bv, bi);
      sel_list[k] = bi;
      scg_sh[bi] = -INFINITY;
    }
    __syncthreads();
  }

  bool selj = false;
#pragma unroll
  for (int k = 0; k < K_; k++) selj = selj || (sel_list[k] == t);

  // ---- softmax over the selected attention logits ----
  if (t == 0) {
    float m = -INFINITY;
    for (int k = 0; k < K_; k++) m = fmaxf(m, attl_sh[sel_list[k]]);
    float ssum = 0.f;
    for (int k = 0; k < K_; k++) ssum += expf(attl_sh[sel_list[k]] - m);
    red_v[0] = m;
    red_v[1] = ssum;
  }
  __syncthreads();
  const float att = selj ? expf(attl_sh[t] - red_v[0]) / red_v[1] : 0.f;

  // ---- outputs ----
  float* __restrict__ ctx_out = out;                                   // [B,N,D]
  float* __restrict__ gate_out = out + B_ * N_ * D_;                   // [B,N,N]
  float* __restrict__ att_out = out + B_ * N_ * D_ + B_ * N_ * N_;     // [B,N,N]

  const int row = (b * N_ + i) * N_;
  gate_out[row + t] = selj ? 1.f : 0.f;
  att_out[row + t] = att;

  __syncthreads();
  attl_sh[t] = att;   // logits no longer needed; reuse as att-weight row
  __syncthreads();

  if (t < D_) {
    float acc = 0.f;
#pragma unroll
    for (int k = 0; k < K_; k++) {
      const int jj = sel_list[k];
      acc = fmaf(attl_sh[jj], s[(b * N_ + jj) * D_ + t], acc);
    }
    ctx_out[(b * N_ + i) * D_ + t] = acc;
  }
}

extern "C" void kernel_launch(void* const* d_in, const int* in_sizes, int n_in,
                              void* d_out, int out_size, void* d_ws, size_t ws_size,
                              hipStream_t stream) {
  const float* s   = (const float*)d_in[0];
  const float* Wg1 = (const float*)d_in[1];
  const float* bg1 = (const float*)d_in[2];
  const float* Wg2 = (const float*)d_in[3];
  const float* bg2 = (const float*)d_in[4];
  const float* Wa1 = (const float*)d_in[5];
  const float* ba1 = (const float*)d_in[6];
  const float* Wa2 = (const float*)d_in[7];
  const float* ba2 = (const float*)d_in[8];
  float* out = (float*)d_out;

  float* ws = (float*)d_ws;
  float* Ag   = ws;                       // B*N*H   = 262144
  float* BgT  = Ag + B_ * N_ * H_;        // B*H*N   = 262144
  float* Aa   = BgT + B_ * H_ * N_;       // 262144
  float* BaT  = Aa + B_ * N_ * H_;        // 262144
  float* WgcT = BaT + B_ * H_ * N_;       // H*D     = 32768
  float* WacT = WgcT + H_ * D_;           // 32768

  prep_kernel<<<dim3(B_ * N_), dim3(256), 0, stream>>>(
      s, Wg1, bg1, Wa1, ba1, Ag, BgT, Aa, BaT, WgcT, WacT);

  score_kernel<<<dim3(B_ * N_), dim3(256), 0, stream>>>(
      s, Ag, BgT, Aa, BaT, WgcT, WacT, Wg2, bg2, Wa2, ba2, out);
}

// Round 4
// 409.993 us; speedup vs baseline: 5.2054x; 5.2054x over previous
//
#include <hip/hip_runtime.h>
#include <math.h>

#define B_ 4
#define N_ 256
#define D_ 128
#define H_ 256
#define K_ 8
#define NH 512    // both nets' hidden units concatenated (g: 0..255, a: 256..511)
#define KK 256    // GEMM K = [p (128) | sj (128)]  (j-bias folded into GEMM)
#define NJP 64    // j per phase (4 phases)
#define LDA 136   // LDS A-tile row stride in bf16 elems (128 + 8 pad, bank-uniform)

typedef short v8s __attribute__((ext_vector_type(8)));   // 8 bf16 = 4 VGPRs
typedef float v4f __attribute__((ext_vector_type(4)));   // MFMA accumulator

// hi = top-16-bit truncation (x - hi is EXACT); lo = RNE bf16 of remainder.
__device__ inline void split_bf16(float x, unsigned short& hi, unsigned short& lo) {
  unsigned u = __float_as_uint(x);
  unsigned uh = u & 0xFFFF0000u;
  hi = (unsigned short)(uh >> 16);
  float r = x - __uint_as_float(uh);
  unsigned ur = __float_as_uint(r);
  ur += 0x7FFFu + ((ur >> 16) & 1u);
  lo = (unsigned short)(ur >> 16);
}

// ---------------------------------------------------------------------------
// prep_an: Ag/Aa (i-side first-layer terms, bias folded) + bf16-split of s.
// ---------------------------------------------------------------------------
__global__ __launch_bounds__(256) void prep_an(
    const float* __restrict__ s,
    const float* __restrict__ Wg1, const float* __restrict__ bg1,
    const float* __restrict__ Wa1, const float* __restrict__ ba1,
    float* __restrict__ Ag, float* __restrict__ Aa,
    unsigned short* __restrict__ Shi, unsigned short* __restrict__ Slo) {
  const int b = blockIdx.x >> 8;
  const int n = blockIdx.x & 255;
  const int h = threadIdx.x;
  __shared__ float sh[D_];
  if (h < D_) sh[h] = s[(b * N_ + n) * D_ + h];
  __syncthreads();
  float ag = bg1[h], aa = ba1[h];
#pragma unroll 8
  for (int d = 0; d < D_; d++) {
    ag = fmaf(sh[d], Wg1[d * H_ + h], ag);
    aa = fmaf(sh[d], Wa1[d * H_ + h], aa);
  }
  Ag[(b * N_ + n) * H_ + h] = ag;
  Aa[(b * N_ + n) * H_ + h] = aa;
  if (h < D_) {
    unsigned short x, y;
    split_bf16(sh[h], x, y);
    Shi[(b * N_ + n) * D_ + h] = x;
    Slo[(b * N_ + n) * D_ + h] = y;
  }
}

// ---------------------------------------------------------------------------
// prep_w: W' split-bf16, laid out [h(512)][k(256)] so B-fragments are 16 B
// contiguous loads. Row h<256: gate net; h>=256: att net.
// k<128 -> Wc row (f=256+k) ; k>=128 -> W1b row (f=k).
// ---------------------------------------------------------------------------
__global__ __launch_bounds__(256) void prep_w(
    const float* __restrict__ Wg1, const float* __restrict__ Wa1,
    unsigned short* __restrict__ Whi, unsigned short* __restrict__ Wlo) {
  const int h = blockIdx.x;       // 0..511
  const int k = threadIdx.x;      // 0..255
  const float* src = (h < H_) ? Wg1 : Wa1;
  const int hh = h & (H_ - 1);
  const int f = (k < D_) ? (2 * D_ + k) : k;
  float w = src[f * H_ + hh];
  unsigned short x, y;
  split_bf16(w, x, y);
  Whi[h * KK + k] = x;
  Wlo[h * KK + k] = y;
}

__device__ inline void arg_better(float v2, int i2, float& v, int& idx) {
  if (v2 > v || (v2 == v && i2 < idx)) { v = v2; idx = i2; }
}

// ---------------------------------------------------------------------------
// score_kernel v4 (MFMA): one block per (b,i), 256 threads = 4 waves.
// Per phase (64 j): stage P hi/lo into LDS; GEMM M=64 x N=512 x K=256 with
// split-3 bf16 MFMA (16x16x32). Wave w owns h-tiles [8w,8w+8).
// A-frags: k<128 from LDS (P), k>=128 from global Shi/Slo (sj rows).
// B-frags: global Whi/Wlo (L2-resident, shared by all blocks).
// Epilogue: z = acc + AgAa[h]; relu; dot W2 -> per-j scores via lane butterfly.
// ---------------------------------------------------------------------------
__global__ __launch_bounds__(256, 2) void score_kernel(
    const float* __restrict__ s,
    const float* __restrict__ Ag, const float* __restrict__ Aa,
    const unsigned short* __restrict__ Shi, const unsigned short* __restrict__ Slo,
    const unsigned short* __restrict__ Whi, const unsigned short* __restrict__ Wlo,
    const float* __restrict__ Wg2, const float* __restrict__ bg2p,
    const float* __restrict__ Wa2, const float* __restrict__ ba2p,
    float* __restrict__ out) {
  const int b = blockIdx.x >> 8;
  const int i = blockIdx.x & 255;
  const int t = threadIdx.x;
  const int wv = t >> 6, lane = t & 63, q = lane >> 4, col = lane & 15;

  __shared__ unsigned short a_hi[NJP * LDA];   // P hi  (17408 B)
  __shared__ unsigned short a_lo[NJP * LDA];   // P lo
  __shared__ float si_sh[D_];
  __shared__ float agaa_sh[NH];
  __shared__ float w2_sh[NH];
  __shared__ float sc_part[4 * NJP];
  __shared__ float scg_sh[N_];
  __shared__ float attl_sh[N_];
  __shared__ float red_v[4];
  __shared__ int red_i[4];
  __shared__ int sel_list[K_];

  if (t < D_) si_sh[t] = s[(b * N_ + i) * D_ + t];
  agaa_sh[t] = Ag[(b * N_ + i) * H_ + t];
  agaa_sh[H_ + t] = Aa[(b * N_ + i) * H_ + t];
  w2_sh[t] = Wg2[t];
  w2_sh[H_ + t] = Wa2[t];

#pragma unroll 1
  for (int ph = 0; ph < 4; ph++) {
    __syncthreads();   // si/agaa ready; prev-phase LDS readers done
    // ---- stage P[jl][d] = si[d]*sj[d] hi/lo into LDS (64 j x 128 d) ----
    {
      const int jl = t >> 2, kq = t & 3;
      const float* srow = s + (b * N_ + ph * NJP + jl) * D_ + kq * 32;
      unsigned short* rh = a_hi + jl * LDA + kq * 32;
      unsigned short* rl = a_lo + jl * LDA + kq * 32;
      const float* sic = si_sh + kq * 32;
#pragma unroll
      for (int u = 0; u < 8; u++) {
        const float4 sv = *(const float4*)(srow + u * 4);
        unsigned short h0, h1, h2, h3, l0, l1, l2, l3;
        split_bf16(sic[u * 4 + 0] * sv.x, h0, l0);
        split_bf16(sic[u * 4 + 1] * sv.y, h1, l1);
        split_bf16(sic[u * 4 + 2] * sv.z, h2, l2);
        split_bf16(sic[u * 4 + 3] * sv.w, h3, l3);
        *(unsigned*)(rh + u * 4)     = (unsigned)h0 | ((unsigned)h1 << 16);
        *(unsigned*)(rh + u * 4 + 2) = (unsigned)h2 | ((unsigned)h3 << 16);
        *(unsigned*)(rl + u * 4)     = (unsigned)l0 | ((unsigned)l1 << 16);
        *(unsigned*)(rl + u * 4 + 2) = (unsigned)l2 | ((unsigned)l3 << 16);
      }
    }
    __syncthreads();

    // ---- GEMM: acc[jt][ht], jt in 0..3 (j), ht in 0..7 (wave's h range) ----
    v4f acc[4][8];
#pragma unroll
    for (int jt = 0; jt < 4; jt++)
#pragma unroll
      for (int ht = 0; ht < 8; ht++) acc[jt][ht] = (v4f){0.f, 0.f, 0.f, 0.f};

    const unsigned short* wh0 = Whi + (wv * 128 + col) * KK + q * 8;
    const unsigned short* wl0 = Wlo + (wv * 128 + col) * KK + q * 8;

#define MFMA3(jt, ht, AH, AL, BH, BL)                                          \
    acc[jt][ht] = __builtin_amdgcn_mfma_f32_16x16x32_bf16(AH, BH, acc[jt][ht], 0, 0, 0); \
    acc[jt][ht] = __builtin_amdgcn_mfma_f32_16x16x32_bf16(AH, BL, acc[jt][ht], 0, 0, 0); \
    acc[jt][ht] = __builtin_amdgcn_mfma_f32_16x16x32_bf16(AL, BH, acc[jt][ht], 0, 0, 0);

    // k-steps 0..3: A from LDS (P part, k<128)
#pragma unroll 1
    for (int ks = 0; ks < 4; ks++) {
      const int ko = ks * 32 + q * 8;
      v8s ah[4], al[4];
#pragma unroll
      for (int jt = 0; jt < 4; jt++) {
        ah[jt] = *(const v8s*)(a_hi + (jt * 16 + col) * LDA + ko);
        al[jt] = *(const v8s*)(a_lo + (jt * 16 + col) * LDA + ko);
      }
#pragma unroll
      for (int ht = 0; ht < 8; ht++) {
        const v8s bh = *(const v8s*)(wh0 + ht * 16 * KK + ks * 32);
        const v8s bl = *(const v8s*)(wl0 + ht * 16 * KK + ks * 32);
        MFMA3(0, ht, ah[0], al[0], bh, bl)
        MFMA3(1, ht, ah[1], al[1], bh, bl)
        MFMA3(2, ht, ah[2], al[2], bh, bl)
        MFMA3(3, ht, ah[3], al[3], bh, bl)
      }
    }
    // k-steps 4..7: A from global Shi/Slo (sj part, k>=128 -> d = k-128)
#pragma unroll 1
    for (int ks = 0; ks < 4; ks++) {
      const int doff = ks * 32 + q * 8;
      v8s ah[4], al[4];
#pragma unroll
      for (int jt = 0; jt < 4; jt++) {
        const int j = b * N_ + ph * NJP + jt * 16 + col;
        ah[jt] = *(const v8s*)(Shi + j * D_ + doff);
        al[jt] = *(const v8s*)(Slo + j * D_ + doff);
      }
#pragma unroll
      for (int ht = 0; ht < 8; ht++) {
        const v8s bh = *(const v8s*)(wh0 + ht * 16 * KK + 128 + ks * 32);
        const v8s bl = *(const v8s*)(wl0 + ht * 16 * KK + 128 + ks * 32);
        MFMA3(0, ht, ah[0], al[0], bh, bl)
        MFMA3(1, ht, ah[1], al[1], bh, bl)
        MFMA3(2, ht, ah[2], al[2], bh, bl)
        MFMA3(3, ht, ah[3], al[3], bh, bl)
      }
    }
#undef MFMA3

    // ---- epilogue: second layer, per-lane partials then 16-lane butterfly ----
    float sc[16];
#pragma unroll
    for (int m = 0; m < 16; m++) sc[m] = 0.f;
#pragma unroll
    for (int ht = 0; ht < 8; ht++) {
      const int h = wv * 128 + ht * 16 + col;
      const float agv = agaa_sh[h];
      const float w2v = w2_sh[h];
#pragma unroll
      for (int jt = 0; jt < 4; jt++)
#pragma unroll
        for (int r = 0; r < 4; r++) {
          const float z = acc[jt][ht][r] + agv;
          sc[jt * 4 + r] = fmaf(fmaxf(z, 0.f), w2v, sc[jt * 4 + r]);
        }
    }
#pragma unroll
    for (int m = 0; m < 16; m++) {
      float v = sc[m];
      v += __shfl_xor(v, 1, 64);
      v += __shfl_xor(v, 2, 64);
      v += __shfl_xor(v, 4, 64);
      v += __shfl_xor(v, 8, 64);
      sc[m] = v;
    }
    if (col == 0) {
#pragma unroll
      for (int jt = 0; jt < 4; jt++)
#pragma unroll
        for (int r = 0; r < 4; r++)
          sc_part[wv * NJP + jt * 16 + q * 4 + r] = sc[jt * 4 + r];
    }
    __syncthreads();
    if (t < NJP) {
      scg_sh[ph * NJP + t] = sc_part[t] + sc_part[NJP + t] + bg2p[0];
      attl_sh[ph * NJP + t] = sc_part[2 * NJP + t] + sc_part[3 * NJP + t] + ba2p[0];
    }
  }
  __syncthreads();

  // ---- top-8 over j: value desc, index asc (verified in R2) ----
  for (int k = 0; k < K_; k++) {
    float v = scg_sh[t];
    int idx = t;
#pragma unroll
    for (int off = 32; off > 0; off >>= 1) {
      const float vo = __shfl_down(v, off, 64);
      const int io = __shfl_down(idx, off, 64);
      arg_better(vo, io, v, idx);
    }
    if ((t & 63) == 0) { red_v[t >> 6] = v; red_i[t >> 6] = idx; }
    __syncthreads();
    if (t == 0) {
      float bv = red_v[0];
      int bi = red_i[0];
      for (int w = 1; w < 4; w++) arg_better(red_v[w], red_i[w], bv, bi);
      sel_list[k] = bi;
      scg_sh[bi] = -INFINITY;
    }
    __syncthreads();
  }

  bool selj = false;
#pragma unroll
  for (int k = 0; k < K_; k++) selj = selj || (sel_list[k] == t);

  // ---- softmax over selected attention logits ----
  if (t == 0) {
    float m = -INFINITY;
    for (int k = 0; k < K_; k++) m = fmaxf(m, attl_sh[sel_list[k]]);
    float ssum = 0.f;
    for (int k = 0; k < K_; k++) ssum += expf(attl_sh[sel_list[k]] - m);
    red_v[0] = m;
    red_v[1] = ssum;
  }
  __syncthreads();
  const float att = selj ? expf(attl_sh[t] - red_v[0]) / red_v[1] : 0.f;

  // ---- outputs ----
  float* __restrict__ ctx_out = out;
  float* __restrict__ gate_out = out + B_ * N_ * D_;
  float* __restrict__ att_out = out + B_ * N_ * D_ + B_ * N_ * N_;

  const int row = (b * N_ + i) * N_;
  gate_out[row + t] = selj ? 1.f : 0.f;
  att_out[row + t] = att;

  __syncthreads();
  attl_sh[t] = att;
  __syncthreads();

  if (t < D_) {
    float acc2 = 0.f;
#pragma unroll
    for (int k = 0; k < K_; k++) {
      const int jj = sel_list[k];
      acc2 = fmaf(attl_sh[jj], s[(b * N_ + jj) * D_ + t], acc2);
    }
    ctx_out[(b * N_ + i) * D_ + t] = acc2;
  }
}

extern "C" void kernel_launch(void* const* d_in, const int* in_sizes, int n_in,
                              void* d_out, int out_size, void* d_ws, size_t ws_size,
                              hipStream_t stream) {
  const float* s   = (const float*)d_in[0];
  const float* Wg1 = (const float*)d_in[1];
  const float* bg1 = (const float*)d_in[2];
  const float* Wg2 = (const float*)d_in[3];
  const float* bg2 = (const float*)d_in[4];
  const float* Wa1 = (const float*)d_in[5];
  const float* ba1 = (const float*)d_in[6];
  const float* Wa2 = (const float*)d_in[7];
  const float* ba2 = (const float*)d_in[8];
  float* out = (float*)d_out;

  float* ws = (float*)d_ws;
  float* Ag = ws;                                   // B*N*H floats
  float* Aa = Ag + B_ * N_ * H_;                    // B*N*H floats
  unsigned short* Whi = (unsigned short*)(Aa + B_ * N_ * H_);  // NH*KK
  unsigned short* Wlo = Whi + NH * KK;
  unsigned short* Shi = Wlo + NH * KK;              // B*N*D
  unsigned short* Slo = Shi + B_ * N_ * D_;

  prep_an<<<dim3(B_ * N_), dim3(256), 0, stream>>>(
      s, Wg1, bg1, Wa1, ba1, Ag, Aa, Shi, Slo);
  prep_w<<<dim3(NH), dim3(256), 0, stream>>>(Wg1, Wa1, Whi, Wlo);
  score_kernel<<<dim3(B_ * N_), dim3(256), 0, stream>>>(
      s, Ag, Aa, Shi, Slo, Whi, Wlo, Wg2, bg2, Wa2, ba2, out);
}

// Round 5
// 363.696 us; speedup vs baseline: 5.8680x; 1.1273x over previous
//
#include <hip/hip_runtime.h>
#include <math.h>

#define B_ 4
#define N_ 256
#define D_ 128
#define H_ 256
#define K_ 8
#define NH 512    // both nets' hidden concat (g: 0..255, a: 256..511)
#define KK 256    // GEMM K = [p (128) | sj (128)]
#define NJP 64    // j per phase (4 phases)
#define LDA 264   // LDS A-tile row stride in bf16 elems (256 + 8 pad)

typedef short v8s __attribute__((ext_vector_type(8)));   // 8 bf16 = 4 VGPRs
typedef float v4f __attribute__((ext_vector_type(4)));   // MFMA accumulator

// hi = top-16-bit truncation (x - hi is EXACT); lo = RNE bf16 of remainder.
__device__ inline void split_bf16(float x, unsigned short& hi, unsigned short& lo) {
  unsigned u = __float_as_uint(x);
  unsigned uh = u & 0xFFFF0000u;
  hi = (unsigned short)(uh >> 16);
  float r = x - __uint_as_float(uh);
  unsigned ur = __float_as_uint(r);
  ur += 0x7FFFu + ((ur >> 16) & 1u);
  lo = (unsigned short)(ur >> 16);
}

__global__ __launch_bounds__(256) void prep_an(
    const float* __restrict__ s,
    const float* __restrict__ Wg1, const float* __restrict__ bg1,
    const float* __restrict__ Wa1, const float* __restrict__ ba1,
    float* __restrict__ Ag, float* __restrict__ Aa,
    unsigned short* __restrict__ Shi, unsigned short* __restrict__ Slo) {
  const int b = blockIdx.x >> 8;
  const int n = blockIdx.x & 255;
  const int h = threadIdx.x;
  __shared__ float sh[D_];
  if (h < D_) sh[h] = s[(b * N_ + n) * D_ + h];
  __syncthreads();
  float ag = bg1[h], aa = ba1[h];
#pragma unroll 8
  for (int d = 0; d < D_; d++) {
    ag = fmaf(sh[d], Wg1[d * H_ + h], ag);
    aa = fmaf(sh[d], Wa1[d * H_ + h], aa);
  }
  Ag[(b * N_ + n) * H_ + h] = ag;
  Aa[(b * N_ + n) * H_ + h] = aa;
  if (h < D_) {
    unsigned short x, y;
    split_bf16(sh[h], x, y);
    Shi[(b * N_ + n) * D_ + h] = x;
    Slo[(b * N_ + n) * D_ + h] = y;
  }
}

__global__ __launch_bounds__(256) void prep_w(
    const float* __restrict__ Wg1, const float* __restrict__ Wa1,
    unsigned short* __restrict__ Whi, unsigned short* __restrict__ Wlo) {
  const int h = blockIdx.x;       // 0..511
  const int k = threadIdx.x;      // 0..255
  const float* src = (h < H_) ? Wg1 : Wa1;
  const int hh = h & (H_ - 1);
  const int f = (k < D_) ? (2 * D_ + k) : k;
  float w = src[f * H_ + hh];
  unsigned short x, y;
  split_bf16(w, x, y);
  Whi[h * KK + k] = x;
  Wlo[h * KK + k] = y;
}

__device__ inline void arg_better(float v2, int i2, float& v, int& idx) {
  if (v2 > v || (v2 == v && i2 < idx)) { v = v2; idx = i2; }
}

// ---------------------------------------------------------------------------
// score_kernel v5: as v4 but (a) full A (k=0..256) staged in LDS, and
// (b) B-frag global loads ping-pong double-buffered at half-ks granularity
// so 48 MFMAs (~930 cyc pipe) cover each load group's L2 latency.
// ---------------------------------------------------------------------------
__global__ __launch_bounds__(256, 2) void score_kernel(
    const float* __restrict__ s,
    const float* __restrict__ Ag, const float* __restrict__ Aa,
    const unsigned short* __restrict__ Shi, const unsigned short* __restrict__ Slo,
    const unsigned short* __restrict__ Whi, const unsigned short* __restrict__ Wlo,
    const float* __restrict__ Wg2, const float* __restrict__ bg2p,
    const float* __restrict__ Wa2, const float* __restrict__ ba2p,
    float* __restrict__ out) {
  const int b = blockIdx.x >> 8;
  const int i = blockIdx.x & 255;
  const int t = threadIdx.x;
  const int wv = t >> 6, lane = t & 63, q = lane >> 4, col = lane & 15;

  __shared__ unsigned short a_hi[NJP * LDA];   // A tile hi (33792 B)
  __shared__ unsigned short a_lo[NJP * LDA];   // A tile lo
  __shared__ float si_sh[D_];
  __shared__ float agaa_sh[NH];
  __shared__ float w2_sh[NH];
  __shared__ float sc_part[4 * NJP];
  __shared__ float scg_sh[N_];
  __shared__ float attl_sh[N_];
  __shared__ float red_v[4];
  __shared__ int red_i[4];
  __shared__ int sel_list[K_];

  if (t < D_) si_sh[t] = s[(b * N_ + i) * D_ + t];
  agaa_sh[t] = Ag[(b * N_ + i) * H_ + t];
  agaa_sh[H_ + t] = Aa[(b * N_ + i) * H_ + t];
  w2_sh[t] = Wg2[t];
  w2_sh[H_ + t] = Wa2[t];

  const unsigned short* __restrict__ wh0 = Whi + (wv * 128 + col) * KK + q * 8;
  const unsigned short* __restrict__ wl0 = Wlo + (wv * 128 + col) * KK + q * 8;

#pragma unroll 1
  for (int ph = 0; ph < 4; ph++) {
    __syncthreads();   // si/agaa ready; prev-phase LDS readers done
    // ---- stage A tile: P hi/lo (k<128) + sj hi/lo (k>=128) ----
    {
      const int jl = t >> 2, kq = t & 3;
      const int jg = b * N_ + ph * NJP + jl;
      const float* srow = s + jg * D_ + kq * 32;
      const float* sic = si_sh + kq * 32;
      unsigned short* rh = a_hi + jl * LDA + kq * 32;
      unsigned short* rl = a_lo + jl * LDA + kq * 32;
#pragma unroll
      for (int u = 0; u < 8; u++) {
        const float4 sv = *(const float4*)(srow + u * 4);
        unsigned short h0, h1, h2, h3, l0, l1, l2, l3;
        split_bf16(sic[u * 4 + 0] * sv.x, h0, l0);
        split_bf16(sic[u * 4 + 1] * sv.y, h1, l1);
        split_bf16(sic[u * 4 + 2] * sv.z, h2, l2);
        split_bf16(sic[u * 4 + 3] * sv.w, h3, l3);
        *(unsigned*)(rh + u * 4)     = (unsigned)h0 | ((unsigned)h1 << 16);
        *(unsigned*)(rh + u * 4 + 2) = (unsigned)h2 | ((unsigned)h3 << 16);
        *(unsigned*)(rl + u * 4)     = (unsigned)l0 | ((unsigned)l1 << 16);
        *(unsigned*)(rl + u * 4 + 2) = (unsigned)l2 | ((unsigned)l3 << 16);
      }
      const unsigned short* shr = Shi + jg * D_ + kq * 32;
      const unsigned short* slr = Slo + jg * D_ + kq * 32;
#pragma unroll
      for (int u = 0; u < 4; u++) {
        *(v8s*)(rh + 128 + u * 8) = *(const v8s*)(shr + u * 8);
        *(v8s*)(rl + 128 + u * 8) = *(const v8s*)(slr + u * 8);
      }
    }
    __syncthreads();

    // ---- GEMM M=64 x N=512 x K=256, split-3 bf16 MFMA, pipelined B ----
    v4f acc[4][8];
#pragma unroll
    for (int jt = 0; jt < 4; jt++)
#pragma unroll
      for (int ht = 0; ht < 8; ht++) acc[jt][ht] = (v4f){0.f, 0.f, 0.f, 0.f};

    v8s bhA[4], blA[4], bhB[4], blB[4];
#pragma unroll
    for (int ht = 0; ht < 4; ht++) {   // preload ks=0, half 0
      bhA[ht] = *(const v8s*)(wh0 + ht * 16 * KK);
      blA[ht] = *(const v8s*)(wl0 + ht * 16 * KK);
    }

#define MFMA3(acc_, AH, AL, BH, BL)                                            \
    acc_ = __builtin_amdgcn_mfma_f32_16x16x32_bf16(AH, BH, acc_, 0, 0, 0);     \
    acc_ = __builtin_amdgcn_mfma_f32_16x16x32_bf16(AH, BL, acc_, 0, 0, 0);     \
    acc_ = __builtin_amdgcn_mfma_f32_16x16x32_bf16(AL, BH, acc_, 0, 0, 0);

#pragma unroll 1
    for (int ks = 0; ks < 8; ks++) {
      const int ko = ks * 32 + q * 8;
      v8s ah[4], al[4];
#pragma unroll
      for (int jt = 0; jt < 4; jt++) {
        ah[jt] = *(const v8s*)(a_hi + (jt * 16 + col) * LDA + ko);
        al[jt] = *(const v8s*)(a_lo + (jt * 16 + col) * LDA + ko);
      }
      // prefetch half 1 of this ks into B-regs
#pragma unroll
      for (int ht = 0; ht < 4; ht++) {
        bhB[ht] = *(const v8s*)(wh0 + (ht + 4) * 16 * KK + ks * 32);
        blB[ht] = *(const v8s*)(wl0 + (ht + 4) * 16 * KK + ks * 32);
      }
      // compute half 0 (uses A-regs)
#pragma unroll
      for (int ht = 0; ht < 4; ht++)
#pragma unroll
        for (int jt = 0; jt < 4; jt++) {
          MFMA3(acc[jt][ht], ah[jt], al[jt], bhA[ht], blA[ht])
        }
      // prefetch half 0 of ks+1 (wrap; last one redundant but harmless)
      const int kn = ((ks + 1) & 7) * 32;
#pragma unroll
      for (int ht = 0; ht < 4; ht++) {
        bhA[ht] = *(const v8s*)(wh0 + ht * 16 * KK + kn);
        blA[ht] = *(const v8s*)(wl0 + ht * 16 * KK + kn);
      }
      // compute half 1 (uses B-regs)
#pragma unroll
      for (int ht = 0; ht < 4; ht++)
#pragma unroll
        for (int jt = 0; jt < 4; jt++) {
          MFMA3(acc[jt][ht + 4], ah[jt], al[jt], bhB[ht], blB[ht])
        }
    }
#undef MFMA3

    // ---- epilogue: second layer + 16-lane butterfly ----
    float sc[16];
#pragma unroll
    for (int m = 0; m < 16; m++) sc[m] = 0.f;
#pragma unroll
    for (int ht = 0; ht < 8; ht++) {
      const int h = wv * 128 + ht * 16 + col;
      const float agv = agaa_sh[h];
      const float w2v = w2_sh[h];
#pragma unroll
      for (int jt = 0; jt < 4; jt++)
#pragma unroll
        for (int r = 0; r < 4; r++) {
          const float z = acc[jt][ht][r] + agv;
          sc[jt * 4 + r] = fmaf(fmaxf(z, 0.f), w2v, sc[jt * 4 + r]);
        }
    }
#pragma unroll
    for (int m = 0; m < 16; m++) {
      float v = sc[m];
      v += __shfl_xor(v, 1, 64);
      v += __shfl_xor(v, 2, 64);
      v += __shfl_xor(v, 4, 64);
      v += __shfl_xor(v, 8, 64);
      sc[m] = v;
    }
    if (col == 0) {
#pragma unroll
      for (int jt = 0; jt < 4; jt++)
#pragma unroll
        for (int r = 0; r < 4; r++)
          sc_part[wv * NJP + jt * 16 + q * 4 + r] = sc[jt * 4 + r];
    }
    __syncthreads();
    if (t < NJP) {
      scg_sh[ph * NJP + t] = sc_part[t] + sc_part[NJP + t] + bg2p[0];
      attl_sh[ph * NJP + t] = sc_part[2 * NJP + t] + sc_part[3 * NJP + t] + ba2p[0];
    }
  }
  __syncthreads();

  // ---- top-8 over j: value desc, index asc ----
  for (int k = 0; k < K_; k++) {
    float v = scg_sh[t];
    int idx = t;
#pragma unroll
    for (int off = 32; off > 0; off >>= 1) {
      const float vo = __shfl_down(v, off, 64);
      const int io = __shfl_down(idx, off, 64);
      arg_better(vo, io, v, idx);
    }
    if ((t & 63) == 0) { red_v[t >> 6] = v; red_i[t >> 6] = idx; }
    __syncthreads();
    if (t == 0) {
      float bv = red_v[0];
      int bi = red_i[0];
      for (int w = 1; w < 4; w++) arg_better(red_v[w], red_i[w], bv, bi);
      sel_list[k] = bi;
      scg_sh[bi] = -INFINITY;
    }
    __syncthreads();
  }

  bool selj = false;
#pragma unroll
  for (int k = 0; k < K_; k++) selj = selj || (sel_list[k] == t);

  if (t == 0) {
    float m = -INFINITY;
    for (int k = 0; k < K_; k++) m = fmaxf(m, attl_sh[sel_list[k]]);
    float ssum = 0.f;
    for (int k = 0; k < K_; k++) ssum += expf(attl_sh[sel_list[k]] - m);
    red_v[0] = m;
    red_v[1] = ssum;
  }
  __syncthreads();
  const float att = selj ? expf(attl_sh[t] - red_v[0]) / red_v[1] : 0.f;

  float* __restrict__ ctx_out = out;
  float* __restrict__ gate_out = out + B_ * N_ * D_;
  float* __restrict__ att_out = out + B_ * N_ * D_ + B_ * N_ * N_;

  const int row = (b * N_ + i) * N_;
  gate_out[row + t] = selj ? 1.f : 0.f;
  att_out[row + t] = att;

  __syncthreads();
  attl_sh[t] = att;
  __syncthreads();

  if (t < D_) {
    float acc2 = 0.f;
#pragma unroll
    for (int k = 0; k < K_; k++) {
      const int jj = sel_list[k];
      acc2 = fmaf(attl_sh[jj], s[(b * N_ + jj) * D_ + t], acc2);
    }
    ctx_out[(b * N_ + i) * D_ + t] = acc2;
  }
}

extern "C" void kernel_launch(void* const* d_in, const int* in_sizes, int n_in,
                              void* d_out, int out_size, void* d_ws, size_t ws_size,
                              hipStream_t stream) {
  const float* s   = (const float*)d_in[0];
  const float* Wg1 = (const float*)d_in[1];
  const float* bg1 = (const float*)d_in[2];
  const float* Wg2 = (const float*)d_in[3];
  const float* bg2 = (const float*)d_in[4];
  const float* Wa1 = (const float*)d_in[5];
  const float* ba1 = (const float*)d_in[6];
  const float* Wa2 = (const float*)d_in[7];
  const float* ba2 = (const float*)d_in[8];
  float* out = (float*)d_out;

  float* ws = (float*)d_ws;
  float* Ag = ws;
  float* Aa = Ag + B_ * N_ * H_;
  unsigned short* Whi = (unsigned short*)(Aa + B_ * N_ * H_);
  unsigned short* Wlo = Whi + NH * KK;
  unsigned short* Shi = Wlo + NH * KK;
  unsigned short* Slo = Shi + B_ * N_ * D_;

  prep_an<<<dim3(B_ * N_), dim3(256), 0, stream>>>(
      s, Wg1, bg1, Wa1, ba1, Ag, Aa, Shi, Slo);
  prep_w<<<dim3(NH), dim3(256), 0, stream>>>(Wg1, Wa1, Whi, Wlo);
  score_kernel<<<dim3(B_ * N_), dim3(256), 0, stream>>>(
      s, Ag, Aa, Shi, Slo, Whi, Wlo, Wg2, bg2, Wa2, ba2, out);
}